// Round 2
// baseline (1570.160 us; speedup 1.0000x reference)
//
#include <hip/hip_runtime.h>
#include <cmath>

#define NLV 16
static constexpr unsigned T_SIZE = 1u << 19;
static constexpr unsigned T_MASK = T_SIZE - 1u;

struct ScaleArgs { float s[NLV]; };

// Dense levels: res^3 <= T. Derived from res = ceil(16*b^l - 1) + 1, b = exp(ln(256)/15).
// l=0..4 -> res {16,24,34,49,71} (71^3=357911 <= 524288); l>=5 hashed.
__global__ void __launch_bounds__(256) hashgrid_mlp_kernel(
    const float* __restrict__ p,
    const float* __restrict__ aabb,
    const float* __restrict__ table,
    const float* __restrict__ w1,
    const float* __restrict__ w2,
    const float* __restrict__ w3,
    float* __restrict__ out,
    int N, ScaleArgs sa)
{
    const int i = blockIdx.x * 256 + threadIdx.x;
    if (i >= N) return;

    const float a0x = aabb[0], a0y = aabb[1], a0z = aabb[2];
    const float a1x = aabb[3], a1y = aabb[4], a1z = aabb[5];

    const float px = p[3 * i + 0], py = p[3 * i + 1], pz = p[3 * i + 2];
    const float x = fminf(fmaxf((px - a0x) / (a1x - a0x), 0.0f), 1.0f);
    const float y = fminf(fmaxf((py - a0y) / (a1y - a0y), 0.0f), 1.0f);
    const float z = fminf(fmaxf((pz - a0z) / (a1z - a0z), 0.0f), 1.0f);

    float enc[2 * NLV];

    constexpr int DENSE_RES[5] = {16, 24, 34, 49, 71};

#pragma unroll
    for (int l = 0; l < NLV; ++l) {
        const float s = sa.s[l];
        const float posx = x * s + 0.5f;
        const float posy = y * s + 0.5f;
        const float posz = z * s + 0.5f;
        const float flx = floorf(posx), fly = floorf(posy), flz = floorf(posz);
        const float fx = posx - flx, fy = posy - fly, fz = posz - flz;
        const int ix = (int)flx, iy = (int)fly, iz = (int)flz;
        const float wx0 = 1.0f - fx, wy0 = 1.0f - fy, wz0 = 1.0f - fz;

        unsigned idx0, idx1, idx2, idx3, idx4, idx5, idx6, idx7;
        if (l < 5) {
            const int res = DENSE_RES[l];
            const unsigned b  = (unsigned)(ix + res * (iy + res * iz));
            const unsigned dy = (unsigned)res;
            const unsigned dz = (unsigned)(res * res);
            idx0 = b;           idx1 = b + 1u;
            idx2 = b + dy;      idx3 = b + dy + 1u;
            idx4 = b + dz;      idx5 = b + dz + 1u;
            idx6 = b + dy + dz; idx7 = b + dy + dz + 1u;
        } else {
            const unsigned hx0 = (unsigned)ix,               hx1 = hx0 + 1u;
            const unsigned hy0 = (unsigned)iy * 2654435761u, hy1 = hy0 + 2654435761u;
            const unsigned hz0 = (unsigned)iz * 805459861u,  hz1 = hz0 + 805459861u;
            idx0 = (hx0 ^ hy0 ^ hz0) & T_MASK;
            idx1 = (hx1 ^ hy0 ^ hz0) & T_MASK;
            idx2 = (hx0 ^ hy1 ^ hz0) & T_MASK;
            idx3 = (hx1 ^ hy1 ^ hz0) & T_MASK;
            idx4 = (hx0 ^ hy0 ^ hz1) & T_MASK;
            idx5 = (hx1 ^ hy0 ^ hz1) & T_MASK;
            idx6 = (hx0 ^ hy1 ^ hz1) & T_MASK;
            idx7 = (hx1 ^ hy1 ^ hz1) & T_MASK;
        }

        const float2* __restrict__ tl =
            reinterpret_cast<const float2*>(table) + (size_t)l * T_SIZE;
        const float2 c0 = tl[idx0], c1 = tl[idx1], c2 = tl[idx2], c3 = tl[idx3];
        const float2 c4 = tl[idx4], c5 = tl[idx5], c6 = tl[idx6], c7 = tl[idx7];

        // corner order matches reference: c bit0 = x, bit1 = y, bit2 = z
        const float w00 = wx0 * wy0, w10 = fx * wy0, w01 = wx0 * fy, w11 = fx * fy;
        const float wa = w00 * wz0, wb = w10 * wz0, wc = w01 * wz0, wd = w11 * wz0;
        const float we = w00 * fz,  wf = w10 * fz,  wg = w01 * fz,  wh = w11 * fz;

        float f0 = wa * c0.x, f1 = wa * c0.y;
        f0 = fmaf(wb, c1.x, f0); f1 = fmaf(wb, c1.y, f1);
        f0 = fmaf(wc, c2.x, f0); f1 = fmaf(wc, c2.y, f1);
        f0 = fmaf(wd, c3.x, f0); f1 = fmaf(wd, c3.y, f1);
        f0 = fmaf(we, c4.x, f0); f1 = fmaf(we, c4.y, f1);
        f0 = fmaf(wf, c5.x, f0); f1 = fmaf(wf, c5.y, f1);
        f0 = fmaf(wg, c6.x, f0); f1 = fmaf(wg, c6.y, f1);
        f0 = fmaf(wh, c7.x, f0); f1 = fmaf(wh, c7.y, f1);

        enc[2 * l]     = f0;   // l is compile-time (full unroll) -> stays in VGPRs
        enc[2 * l + 1] = f1;
    }

    // MLP: weights read with wave-uniform compile-time offsets -> s_load + SGPR-operand FMA
    float h[32];
#pragma unroll
    for (int j = 0; j < 32; ++j) {
        float acc = 0.0f;
#pragma unroll
        for (int k = 0; k < 32; ++k) acc = fmaf(w1[32 * j + k], enc[k], acc);
        h[j] = fmaxf(acc, 0.0f);
    }
    float g[32];
#pragma unroll
    for (int j = 0; j < 32; ++j) {
        float acc = 0.0f;
#pragma unroll
        for (int k = 0; k < 32; ++k) acc = fmaf(w2[32 * j + k], h[k], acc);
        g[j] = fmaxf(acc, 0.0f);
    }
    float o[4];
#pragma unroll
    for (int j = 0; j < 4; ++j) {
        float acc = 0.0f;
#pragma unroll
        for (int k = 0; k < 32; ++k) acc = fmaf(w3[32 * j + k], g[k], acc);
        o[j] = acc;
    }
    reinterpret_cast<float4*>(out)[i] = make_float4(o[0], o[1], o[2], o[3]);
}

extern "C" void kernel_launch(void* const* d_in, const int* in_sizes, int n_in,
                              void* d_out, int out_size, void* d_ws, size_t ws_size,
                              hipStream_t stream) {
    const float* p     = (const float*)d_in[0];
    const float* aabb  = (const float*)d_in[1];
    const float* table = (const float*)d_in[2];
    const float* w1    = (const float*)d_in[3];
    const float* w2    = (const float*)d_in[4];
    const float* w3    = (const float*)d_in[5];
    float* out = (float*)d_out;
    const int N = in_sizes[0] / 3;

    // per-level scales computed in double, cast to f32 (matches JAX weak-type promotion)
    ScaleArgs sa;
    const double b = exp(log(4096.0 / 16.0) / (double)(NLV - 1));
    for (int l = 0; l < NLV; ++l) {
        sa.s[l] = (float)(16.0 * pow(b, (double)l) - 1.0);
    }

    const int threads = 256;
    const int blocks = (N + threads - 1) / threads;
    hipLaunchKernelGGL(hashgrid_mlp_kernel, dim3(blocks), dim3(threads), 0, stream,
                       p, aabb, table, w1, w2, w3, out, N, sa);
}

// Round 7
// 1013.805 us; speedup vs baseline: 1.5488x; 1.5488x over previous
//
#include <hip/hip_runtime.h>
#include <cmath>

#define NLV 16
static constexpr unsigned T_SIZE = 1u << 19;
static constexpr unsigned T_MASK = T_SIZE - 1u;

struct ScaleArgs { float s[NLV]; };

__device__ __forceinline__ float3 normalize_pt(const float* __restrict__ p,
                                               const float* __restrict__ aabb, int i) {
    const float a0x = aabb[0], a0y = aabb[1], a0z = aabb[2];
    const float a1x = aabb[3], a1y = aabb[4], a1z = aabb[5];
    const float px = p[3 * i + 0], py = p[3 * i + 1], pz = p[3 * i + 2];
    float3 r;
    r.x = fminf(fmaxf((px - a0x) / (a1x - a0x), 0.0f), 1.0f);
    r.y = fminf(fmaxf((py - a0y) / (a1y - a0y), 0.0f), 1.0f);
    r.z = fminf(fmaxf((pz - a0z) / (a1z - a0z), 0.0f), 1.0f);
    return r;
}

// ---- dense levels 0..4 (tables total 4.3 MB -> L2-resident) ----
__global__ void __launch_bounds__(256) dense_encode_kernel(
    const float* __restrict__ p, const float* __restrict__ aabb,
    const float* __restrict__ table, float2* __restrict__ enc,
    int N, ScaleArgs sa)
{
    const int i = blockIdx.x * 256 + threadIdx.x;
    if (i >= N) return;
    const float3 u = normalize_pt(p, aabb, i);

    constexpr int DENSE_RES[5] = {16, 24, 34, 49, 71};
#pragma unroll
    for (int l = 0; l < 5; ++l) {
        const float s = sa.s[l];
        const float posx = u.x * s + 0.5f;
        const float posy = u.y * s + 0.5f;
        const float posz = u.z * s + 0.5f;
        const float flx = floorf(posx), fly = floorf(posy), flz = floorf(posz);
        const float fx = posx - flx, fy = posy - fly, fz = posz - flz;
        const int ix = (int)flx, iy = (int)fly, iz = (int)flz;
        const float wx0 = 1.0f - fx, wy0 = 1.0f - fy, wz0 = 1.0f - fz;

        const int res = DENSE_RES[l];
        const unsigned b  = (unsigned)(ix + res * (iy + res * iz));
        const unsigned dy = (unsigned)res;
        const unsigned dz = (unsigned)(res * res);
        const unsigned idx0 = b,           idx1 = b + 1u;
        const unsigned idx2 = b + dy,      idx3 = b + dy + 1u;
        const unsigned idx4 = b + dz,      idx5 = b + dz + 1u;
        const unsigned idx6 = b + dy + dz, idx7 = b + dy + dz + 1u;

        const float2* __restrict__ tl =
            reinterpret_cast<const float2*>(table) + (size_t)l * T_SIZE;
        const float2 c0 = tl[idx0], c1 = tl[idx1], c2 = tl[idx2], c3 = tl[idx3];
        const float2 c4 = tl[idx4], c5 = tl[idx5], c6 = tl[idx6], c7 = tl[idx7];

        const float w00 = wx0 * wy0, w10 = fx * wy0, w01 = wx0 * fy, w11 = fx * fy;
        const float wa = w00 * wz0, wb = w10 * wz0, wc = w01 * wz0, wd = w11 * wz0;
        const float we = w00 * fz,  wf = w10 * fz,  wg = w01 * fz,  wh = w11 * fz;

        float f0 = wa * c0.x, f1 = wa * c0.y;
        f0 = fmaf(wb, c1.x, f0); f1 = fmaf(wb, c1.y, f1);
        f0 = fmaf(wc, c2.x, f0); f1 = fmaf(wc, c2.y, f1);
        f0 = fmaf(wd, c3.x, f0); f1 = fmaf(wd, c3.y, f1);
        f0 = fmaf(we, c4.x, f0); f1 = fmaf(we, c4.y, f1);
        f0 = fmaf(wf, c5.x, f0); f1 = fmaf(wf, c5.y, f1);
        f0 = fmaf(wg, c6.x, f0); f1 = fmaf(wg, c6.y, f1);
        f0 = fmaf(wh, c7.x, f0); f1 = fmaf(wh, c7.y, f1);

        enc[(size_t)l * N + i] = make_float2(f0, f1);
    }
}

// ---- one hashed level per launch: 4 MiB slice == one XCD L2, phased ----
template<int L>
__global__ void __launch_bounds__(256) hash_encode_kernel(
    const float* __restrict__ p, const float* __restrict__ aabb,
    const float* __restrict__ table, float2* __restrict__ enc,
    int N, float s)
{
    const int i = blockIdx.x * 256 + threadIdx.x;
    if (i >= N) return;
    const float3 u = normalize_pt(p, aabb, i);

    const float posx = u.x * s + 0.5f;
    const float posy = u.y * s + 0.5f;
    const float posz = u.z * s + 0.5f;
    const float flx = floorf(posx), fly = floorf(posy), flz = floorf(posz);
    const float fx = posx - flx, fy = posy - fly, fz = posz - flz;
    const int ix = (int)flx, iy = (int)fly, iz = (int)flz;
    const float wx0 = 1.0f - fx, wy0 = 1.0f - fy, wz0 = 1.0f - fz;

    const unsigned hx0 = (unsigned)ix,               hx1 = hx0 + 1u;
    const unsigned hy0 = (unsigned)iy * 2654435761u, hy1 = hy0 + 2654435761u;
    const unsigned hz0 = (unsigned)iz * 805459861u,  hz1 = hz0 + 805459861u;
    const unsigned idx0 = (hx0 ^ hy0 ^ hz0) & T_MASK;
    const unsigned idx1 = (hx1 ^ hy0 ^ hz0) & T_MASK;
    const unsigned idx2 = (hx0 ^ hy1 ^ hz0) & T_MASK;
    const unsigned idx3 = (hx1 ^ hy1 ^ hz0) & T_MASK;
    const unsigned idx4 = (hx0 ^ hy0 ^ hz1) & T_MASK;
    const unsigned idx5 = (hx1 ^ hy0 ^ hz1) & T_MASK;
    const unsigned idx6 = (hx0 ^ hy1 ^ hz1) & T_MASK;
    const unsigned idx7 = (hx1 ^ hy1 ^ hz1) & T_MASK;

    const float2* __restrict__ tl =
        reinterpret_cast<const float2*>(table) + (size_t)L * T_SIZE;
    const float2 c0 = tl[idx0], c1 = tl[idx1], c2 = tl[idx2], c3 = tl[idx3];
    const float2 c4 = tl[idx4], c5 = tl[idx5], c6 = tl[idx6], c7 = tl[idx7];

    const float w00 = wx0 * wy0, w10 = fx * wy0, w01 = wx0 * fy, w11 = fx * fy;
    const float wa = w00 * wz0, wb = w10 * wz0, wc = w01 * wz0, wd = w11 * wz0;
    const float we = w00 * fz,  wf = w10 * fz,  wg = w01 * fz,  wh = w11 * fz;

    float f0 = wa * c0.x, f1 = wa * c0.y;
    f0 = fmaf(wb, c1.x, f0); f1 = fmaf(wb, c1.y, f1);
    f0 = fmaf(wc, c2.x, f0); f1 = fmaf(wc, c2.y, f1);
    f0 = fmaf(wd, c3.x, f0); f1 = fmaf(wd, c3.y, f1);
    f0 = fmaf(we, c4.x, f0); f1 = fmaf(we, c4.y, f1);
    f0 = fmaf(wf, c5.x, f0); f1 = fmaf(wf, c5.y, f1);
    f0 = fmaf(wg, c6.x, f0); f1 = fmaf(wg, c6.y, f1);
    f0 = fmaf(wh, c7.x, f0); f1 = fmaf(wh, c7.y, f1);

    enc[(size_t)L * N + i] = make_float2(f0, f1);
}

// ---- MLP over staged features ----
__global__ void __launch_bounds__(256) mlp_kernel(
    const float2* __restrict__ enc,
    const float* __restrict__ w1, const float* __restrict__ w2,
    const float* __restrict__ w3, float* __restrict__ out, int N)
{
    const int i = blockIdx.x * 256 + threadIdx.x;
    if (i >= N) return;

    float e[32];
#pragma unroll
    for (int l = 0; l < NLV; ++l) {
        const float2 v = enc[(size_t)l * N + i];
        e[2 * l] = v.x; e[2 * l + 1] = v.y;
    }

    float h[32];
#pragma unroll
    for (int j = 0; j < 32; ++j) {
        float acc = 0.0f;
#pragma unroll
        for (int k = 0; k < 32; ++k) acc = fmaf(w1[32 * j + k], e[k], acc);
        h[j] = fmaxf(acc, 0.0f);
    }
    float g[32];
#pragma unroll
    for (int j = 0; j < 32; ++j) {
        float acc = 0.0f;
#pragma unroll
        for (int k = 0; k < 32; ++k) acc = fmaf(w2[32 * j + k], h[k], acc);
        g[j] = fmaxf(acc, 0.0f);
    }
    float o[4];
#pragma unroll
    for (int j = 0; j < 4; ++j) {
        float acc = 0.0f;
#pragma unroll
        for (int k = 0; k < 32; ++k) acc = fmaf(w3[32 * j + k], g[k], acc);
        o[j] = acc;
    }
    reinterpret_cast<float4*>(out)[i] = make_float4(o[0], o[1], o[2], o[3]);
}

// ---- fallback: round-0 fused kernel (used only if ws too small) ----
__global__ void __launch_bounds__(256) hashgrid_mlp_kernel(
    const float* __restrict__ p, const float* __restrict__ aabb,
    const float* __restrict__ table,
    const float* __restrict__ w1, const float* __restrict__ w2,
    const float* __restrict__ w3, float* __restrict__ out,
    int N, ScaleArgs sa)
{
    const int i = blockIdx.x * 256 + threadIdx.x;
    if (i >= N) return;
    const float3 u = normalize_pt(p, aabb, i);

    float enc[2 * NLV];
    constexpr int DENSE_RES[5] = {16, 24, 34, 49, 71};
#pragma unroll
    for (int l = 0; l < NLV; ++l) {
        const float s = sa.s[l];
        const float posx = u.x * s + 0.5f;
        const float posy = u.y * s + 0.5f;
        const float posz = u.z * s + 0.5f;
        const float flx = floorf(posx), fly = floorf(posy), flz = floorf(posz);
        const float fx = posx - flx, fy = posy - fly, fz = posz - flz;
        const int ix = (int)flx, iy = (int)fly, iz = (int)flz;
        const float wx0 = 1.0f - fx, wy0 = 1.0f - fy, wz0 = 1.0f - fz;

        unsigned idx0, idx1, idx2, idx3, idx4, idx5, idx6, idx7;
        if (l < 5) {
            const int res = DENSE_RES[l];
            const unsigned b  = (unsigned)(ix + res * (iy + res * iz));
            const unsigned dy = (unsigned)res;
            const unsigned dz = (unsigned)(res * res);
            idx0 = b;           idx1 = b + 1u;
            idx2 = b + dy;      idx3 = b + dy + 1u;
            idx4 = b + dz;      idx5 = b + dz + 1u;
            idx6 = b + dy + dz; idx7 = b + dy + dz + 1u;
        } else {
            const unsigned hx0 = (unsigned)ix,               hx1 = hx0 + 1u;
            const unsigned hy0 = (unsigned)iy * 2654435761u, hy1 = hy0 + 2654435761u;
            const unsigned hz0 = (unsigned)iz * 805459861u,  hz1 = hz0 + 805459861u;
            idx0 = (hx0 ^ hy0 ^ hz0) & T_MASK;
            idx1 = (hx1 ^ hy0 ^ hz0) & T_MASK;
            idx2 = (hx0 ^ hy1 ^ hz0) & T_MASK;
            idx3 = (hx1 ^ hy1 ^ hz0) & T_MASK;
            idx4 = (hx0 ^ hy0 ^ hz1) & T_MASK;
            idx5 = (hx1 ^ hy0 ^ hz1) & T_MASK;
            idx6 = (hx0 ^ hy1 ^ hz1) & T_MASK;
            idx7 = (hx1 ^ hy1 ^ hz1) & T_MASK;
        }

        const float2* __restrict__ tl =
            reinterpret_cast<const float2*>(table) + (size_t)l * T_SIZE;
        const float2 c0 = tl[idx0], c1 = tl[idx1], c2 = tl[idx2], c3 = tl[idx3];
        const float2 c4 = tl[idx4], c5 = tl[idx5], c6 = tl[idx6], c7 = tl[idx7];

        const float w00 = wx0 * wy0, w10 = fx * wy0, w01 = wx0 * fy, w11 = fx * fy;
        const float wa = w00 * wz0, wb = w10 * wz0, wc = w01 * wz0, wd = w11 * wz0;
        const float we = w00 * fz,  wf = w10 * fz,  wg = w01 * fz,  wh = w11 * fz;

        float f0 = wa * c0.x, f1 = wa * c0.y;
        f0 = fmaf(wb, c1.x, f0); f1 = fmaf(wb, c1.y, f1);
        f0 = fmaf(wc, c2.x, f0); f1 = fmaf(wc, c2.y, f1);
        f0 = fmaf(wd, c3.x, f0); f1 = fmaf(wd, c3.y, f1);
        f0 = fmaf(we, c4.x, f0); f1 = fmaf(we, c4.y, f1);
        f0 = fmaf(wf, c5.x, f0); f1 = fmaf(wf, c5.y, f1);
        f0 = fmaf(wg, c6.x, f0); f1 = fmaf(wg, c6.y, f1);
        f0 = fmaf(wh, c7.x, f0); f1 = fmaf(wh, c7.y, f1);

        enc[2 * l] = f0; enc[2 * l + 1] = f1;
    }

    float h[32];
#pragma unroll
    for (int j = 0; j < 32; ++j) {
        float acc = 0.0f;
#pragma unroll
        for (int k = 0; k < 32; ++k) acc = fmaf(w1[32 * j + k], enc[k], acc);
        h[j] = fmaxf(acc, 0.0f);
    }
    float g[32];
#pragma unroll
    for (int j = 0; j < 32; ++j) {
        float acc = 0.0f;
#pragma unroll
        for (int k = 0; k < 32; ++k) acc = fmaf(w2[32 * j + k], h[k], acc);
        g[j] = fmaxf(acc, 0.0f);
    }
    float o[4];
#pragma unroll
    for (int j = 0; j < 4; ++j) {
        float acc = 0.0f;
#pragma unroll
        for (int k = 0; k < 32; ++k) acc = fmaf(w3[32 * j + k], g[k], acc);
        o[j] = acc;
    }
    reinterpret_cast<float4*>(out)[i] = make_float4(o[0], o[1], o[2], o[3]);
}

extern "C" void kernel_launch(void* const* d_in, const int* in_sizes, int n_in,
                              void* d_out, int out_size, void* d_ws, size_t ws_size,
                              hipStream_t stream) {
    const float* p     = (const float*)d_in[0];
    const float* aabb  = (const float*)d_in[1];
    const float* table = (const float*)d_in[2];
    const float* w1    = (const float*)d_in[3];
    const float* w2    = (const float*)d_in[4];
    const float* w3    = (const float*)d_in[5];
    float* out = (float*)d_out;
    const int N = in_sizes[0] / 3;

    ScaleArgs sa;
    const double b = exp(log(4096.0 / 16.0) / (double)(NLV - 1));
    for (int l = 0; l < NLV; ++l) sa.s[l] = (float)(16.0 * pow(b, (double)l) - 1.0);

    const int threads = 256;
    const int blocks = (N + threads - 1) / threads;
    const size_t need = (size_t)N * NLV * sizeof(float2);

    if (ws_size >= need) {
        float2* enc = (float2*)d_ws;
        hipLaunchKernelGGL(dense_encode_kernel, dim3(blocks), dim3(threads), 0, stream,
                           p, aabb, table, enc, N, sa);
#define LAUNCH_HASH(L) \
        hipLaunchKernelGGL(hash_encode_kernel<L>, dim3(blocks), dim3(threads), 0, stream, \
                           p, aabb, table, enc, N, sa.s[L])
        LAUNCH_HASH(5);  LAUNCH_HASH(6);  LAUNCH_HASH(7);  LAUNCH_HASH(8);
        LAUNCH_HASH(9);  LAUNCH_HASH(10); LAUNCH_HASH(11); LAUNCH_HASH(12);
        LAUNCH_HASH(13); LAUNCH_HASH(14); LAUNCH_HASH(15);
#undef LAUNCH_HASH
        hipLaunchKernelGGL(mlp_kernel, dim3(blocks), dim3(threads), 0, stream,
                           enc, w1, w2, w3, out, N);
    } else {
        hipLaunchKernelGGL(hashgrid_mlp_kernel, dim3(blocks), dim3(threads), 0, stream,
                           p, aabb, table, w1, w2, w3, out, N, sa);
    }
}